// Round 1
// baseline (77.378 us; speedup 1.0000x reference)
//
#include <hip/hip_runtime.h>
#include <hip/hip_bf16.h>
#include <stdint.h>

#define MB_ 16384
#define NN_ 1024
#define KK_ 1024

typedef __bf16 bhalf;
typedef __bf16 bhalf8 __attribute__((ext_vector_type(8)));
typedef __bf16 bhalf4 __attribute__((ext_vector_type(4)));
typedef float f32x4 __attribute__((ext_vector_type(4)));

typedef const __attribute__((address_space(1))) void* gas_ptr;
typedef __attribute__((address_space(3))) void* las_ptr;

__device__ __forceinline__ void gload_lds16(const void* g, void* l) {
  __builtin_amdgcn_global_load_lds((gas_ptr)g, (las_ptr)l, 16, 0, 0);
}

// ---------------- K1a: partial column max / sumexp ----------------
// grid (4, 32), block 256. col = bx*256+tid, rows by*32 .. +32
__global__ void k_colpart(const float* __restrict__ W,
                          float* __restrict__ pM, float* __restrict__ pS) {
  int col = blockIdx.x * 256 + threadIdx.x;
  int rc  = blockIdx.y;
  const float* p = W + (size_t)rc * 32 * NN_ + col;
  float v[32];
#pragma unroll
  for (int i = 0; i < 32; ++i) v[i] = p[(size_t)i * NN_];
  float m = v[0];
#pragma unroll
  for (int i = 1; i < 32; ++i) m = fmaxf(m, v[i]);
  float s = 0.f;
#pragma unroll
  for (int i = 0; i < 32; ++i) s += __expf(v[i] - m);
  pM[rc * NN_ + col] = m;
  pS[rc * NN_ + col] = s;
}

// ---------------- K1b: combine partials -> colLSE ----------------
// grid 4, block 256
__global__ void k_colfin(const float* __restrict__ pM, const float* __restrict__ pS,
                         float* __restrict__ colLSE) {
  int col = blockIdx.x * 256 + threadIdx.x;
  float m = -1e30f;
#pragma unroll
  for (int i = 0; i < 32; ++i) m = fmaxf(m, pM[i * NN_ + col]);
  float s = 0.f;
#pragma unroll
  for (int i = 0; i < 32; ++i) s += pS[i * NN_ + col] * __expf(pM[i * NN_ + col] - m);
  colLSE[col] = m + __logf(s);
}

// ---------------- K2: expA[i,k] = exp(W[i,k]-colLSE[k]-mA[i]), mA[i] ----------------
// grid 1024, block 64 (one wave per row)
__global__ void k_expA(const float* __restrict__ W, const float* __restrict__ colLSE,
                       bhalf* __restrict__ eA, float* __restrict__ mA) {
  int i = blockIdx.x;
  int l = threadIdx.x;
  const float4* row = (const float4*)(W + (size_t)i * NN_);
  const float4* cls = (const float4*)colLSE;
  float4 v[4];
#pragma unroll
  for (int t = 0; t < 4; ++t) {
    float4 wv = row[t * 64 + l];
    float4 cv = cls[t * 64 + l];
    v[t].x = wv.x - cv.x; v[t].y = wv.y - cv.y;
    v[t].z = wv.z - cv.z; v[t].w = wv.w - cv.w;
  }
  float m = -1e30f;
#pragma unroll
  for (int t = 0; t < 4; ++t)
    m = fmaxf(m, fmaxf(fmaxf(v[t].x, v[t].y), fmaxf(v[t].z, v[t].w)));
#pragma unroll
  for (int off = 32; off; off >>= 1) m = fmaxf(m, __shfl_xor(m, off));
#pragma unroll
  for (int t = 0; t < 4; ++t) {
    bhalf4 o;
    o[0] = (bhalf)__expf(v[t].x - m);
    o[1] = (bhalf)__expf(v[t].y - m);
    o[2] = (bhalf)__expf(v[t].z - m);
    o[3] = (bhalf)__expf(v[t].w - m);
    *(bhalf4*)(eA + (size_t)i * NN_ + t * 256 + l * 4) = o;
  }
  if (l == 0) mA[i] = m;
}

// ---------------- K3: expB[b,k] = exp(la[b,k]-mB[b]), mB[b] ----------------
// grid 16384, block 64
__global__ void k_expB(const float* __restrict__ LA,
                       bhalf* __restrict__ eB, float* __restrict__ mB) {
  int b = blockIdx.x;
  int l = threadIdx.x;
  const float4* row = (const float4*)(LA + (size_t)b * NN_);
  float4 v[4];
#pragma unroll
  for (int t = 0; t < 4; ++t) v[t] = row[t * 64 + l];
  float m = -1e30f;
#pragma unroll
  for (int t = 0; t < 4; ++t)
    m = fmaxf(m, fmaxf(fmaxf(v[t].x, v[t].y), fmaxf(v[t].z, v[t].w)));
#pragma unroll
  for (int off = 32; off; off >>= 1) m = fmaxf(m, __shfl_xor(m, off));
#pragma unroll
  for (int t = 0; t < 4; ++t) {
    bhalf4 o;
    o[0] = (bhalf)__expf(v[t].x - m);
    o[1] = (bhalf)__expf(v[t].y - m);
    o[2] = (bhalf)__expf(v[t].z - m);
    o[3] = (bhalf)__expf(v[t].w - m);
    *(bhalf4*)(eB + (size_t)b * NN_ + t * 256 + l * 4) = o;
  }
  if (l == 0) mB[b] = m;
}

// ---------------- GEMM: out[b,i] = log(sum_k eB[b,k]*eA[i,k]) + mB[b] + mA[i] ----------------
// 128x128 tile, BK=64, 256 threads (4 waves, 2x2), mfma 16x16x32 bf16
// LDS linear dest for global_load_lds; XOR swizzle applied on global src + ds_read.
__global__ __launch_bounds__(256) void k_gemm(const bhalf* __restrict__ A,  // eB [M][K]
                                              const bhalf* __restrict__ Bt, // eA [N][K]
                                              const float* __restrict__ mB,
                                              const float* __restrict__ mA,
                                              float* __restrict__ out) {
  __shared__ __align__(16) unsigned char lds[32768];
  unsigned char* sA = lds;
  unsigned char* sB = lds + 16384;

  int nwg = gridDim.x;            // 1024, divisible by 8
  int cpx = nwg >> 3;
  int wg  = blockIdx.x;
  int swz = (wg & 7) * cpx + (wg >> 3);
  int bm = swz >> 3;              // 0..127
  int bn = swz & 7;               // 0..7

  int tid = threadIdx.x;
  int w = tid >> 6, l = tid & 63;
  int wr = w >> 1, wc = w & 1;

  f32x4 zero = {0.f, 0.f, 0.f, 0.f};
  f32x4 acc[4][4];
#pragma unroll
  for (int m = 0; m < 4; ++m)
#pragma unroll
    for (int n = 0; n < 4; ++n) acc[m][n] = zero;

  // staging: per call c, lane l covers LDS bytes c*4096 + w*1024 + l*16
  // -> row r = c*32 + w*8 + (l>>3), 16B chunk j = l&7.
  // swizzled source chunk = j ^ (r&7) = (l&7) ^ (l>>3)
  const int lr = l >> 3;
  const int kel = (((l & 7) ^ lr) << 3);  // element offset of source chunk
  const bhalf* gA = A  + (size_t)(bm * 128 + w * 8 + lr) * KK_ + kel;
  const bhalf* gB = Bt + (size_t)(bn * 128 + w * 8 + lr) * KK_ + kel;
  unsigned char* lA = sA + w * 1024 + l * 16;
  unsigned char* lB = sB + w * 1024 + l * 16;

  const int rba = wr * 64 + (l & 15);   // A frag row base
  const int rbb = wc * 64 + (l & 15);   // B frag row base (output col)
  const int kx  = 16 * (l >> 4);        // byte offset of lane group's k-chunk

  for (int kt = 0; kt < KK_ / 64; ++kt) {
    if (kt) __syncthreads();
    const bhalf* ga = gA + kt * 64;
    const bhalf* gb = gB + kt * 64;
#pragma unroll
    for (int c = 0; c < 4; ++c) {
      gload_lds16(ga + (size_t)c * 32 * KK_, lA + c * 4096);
      gload_lds16(gb + (size_t)c * 32 * KK_, lB + c * 4096);
    }
    __syncthreads();
#pragma unroll
    for (int kk = 0; kk < 2; ++kk) {
      bhalf8 af[4], bq[4];
#pragma unroll
      for (int m = 0; m < 4; ++m) {
        int row = rba + m * 16;
        af[m] = *(const bhalf8*)(sA + row * 128 + ((kk * 64 + kx) ^ ((row & 7) << 4)));
      }
#pragma unroll
      for (int n = 0; n < 4; ++n) {
        int row = rbb + n * 16;
        bq[n] = *(const bhalf8*)(sB + row * 128 + ((kk * 64 + kx) ^ ((row & 7) << 4)));
      }
#pragma unroll
      for (int m = 0; m < 4; ++m)
#pragma unroll
        for (int n = 0; n < 4; ++n)
          acc[m][n] = __builtin_amdgcn_mfma_f32_16x16x32_bf16(af[m], bq[n], acc[m][n], 0, 0, 0);
    }
  }

  // epilogue: D row = 4*(l>>4)+r, col = l&15
  int c0 = bn * 128 + wc * 64 + (l & 15);
  int r0 = bm * 128 + wr * 64 + (l >> 4) * 4;
#pragma unroll
  for (int n = 0; n < 4; ++n) {
    float ma = mA[c0 + n * 16];
#pragma unroll
    for (int m = 0; m < 4; ++m) {
#pragma unroll
      for (int r = 0; r < 4; ++r) {
        int row = r0 + m * 16 + r;
        out[(size_t)row * NN_ + c0 + n * 16] = __logf(acc[m][n][r]) + mB[row] + ma;
      }
    }
  }
}

extern "C" void kernel_launch(void* const* d_in, const int* in_sizes, int n_in,
                              void* d_out, int out_size, void* d_ws, size_t ws_size,
                              hipStream_t stream) {
  const float* log_alpha = (const float*)d_in[0];  // [16384,1024] f32
  const float* W         = (const float*)d_in[1];  // [1024,1024] f32
  float* out = (float*)d_out;                      // [16384,1024] f32

  uintptr_t ws = (uintptr_t)d_ws;
  bhalf* eB     = (bhalf*)(ws);                    // 33,554,432 B
  bhalf* eA     = (bhalf*)(ws + 33554432);         //  2,097,152 B
  float* mB     = (float*)(ws + 35651584);         //     65,536 B
  float* mA     = (float*)(ws + 35717120);         //      4,096 B
  float* colLSE = (float*)(ws + 35721216);         //      4,096 B
  float* pM     = (float*)(ws + 35725312);         //    131,072 B
  float* pS     = (float*)(ws + 35856384);         //    131,072 B

  k_colpart<<<dim3(4, 32), 256, 0, stream>>>(W, pM, pS);
  k_colfin<<<4, 256, 0, stream>>>(pM, pS, colLSE);
  k_expA<<<NN_, 64, 0, stream>>>(W, colLSE, eA, mA);
  k_expB<<<MB_, 64, 0, stream>>>(log_alpha, eB, mB);
  k_gemm<<<(MB_ / 128) * (NN_ / 128), 256, 0, stream>>>(eB, eA, mB, mA, out);
}

// Round 2
// 69.533 us; speedup vs baseline: 1.1128x; 1.1128x over previous
//
#include <hip/hip_runtime.h>
#include <hip/hip_bf16.h>
#include <stdint.h>

#define MB_ 16384
#define NN_ 1024
#define KK_ 1024

typedef __bf16 bhalf;
typedef __bf16 bhalf8 __attribute__((ext_vector_type(8)));
typedef __bf16 bhalf4 __attribute__((ext_vector_type(4)));
typedef float f32x4 __attribute__((ext_vector_type(4)));

typedef const __attribute__((address_space(1))) void* gas_ptr;
typedef __attribute__((address_space(3))) void* las_ptr;

__device__ __forceinline__ void gload_lds16(const void* g, void* l) {
  __builtin_amdgcn_global_load_lds((gas_ptr)g, (las_ptr)l, 16, 0, 0);
}

// ---------------- K1a: partial column max / sumexp ----------------
__global__ void k_colpart(const float* __restrict__ W,
                          float* __restrict__ pM, float* __restrict__ pS) {
  int col = blockIdx.x * 256 + threadIdx.x;
  int rc  = blockIdx.y;
  const float* p = W + (size_t)rc * 32 * NN_ + col;
  float v[32];
#pragma unroll
  for (int i = 0; i < 32; ++i) v[i] = p[(size_t)i * NN_];
  float m = v[0];
#pragma unroll
  for (int i = 1; i < 32; ++i) m = fmaxf(m, v[i]);
  float s = 0.f;
#pragma unroll
  for (int i = 0; i < 32; ++i) s += __expf(v[i] - m);
  pM[rc * NN_ + col] = m;
  pS[rc * NN_ + col] = s;
}

// ---------------- K1b: combine partials -> colLSE ----------------
__global__ void k_colfin(const float* __restrict__ pM, const float* __restrict__ pS,
                         float* __restrict__ colLSE) {
  int col = blockIdx.x * 256 + threadIdx.x;
  float m = -1e30f;
#pragma unroll
  for (int i = 0; i < 32; ++i) m = fmaxf(m, pM[i * NN_ + col]);
  float s = 0.f;
#pragma unroll
  for (int i = 0; i < 32; ++i) s += pS[i * NN_ + col] * __expf(pM[i * NN_ + col] - m);
  colLSE[col] = m + __logf(s);
}

// ---------------- K2: expA[i,k] = exp(W[i,k]-colLSE[k]-mA[i]), mA[i] ----------------
__global__ void k_expA(const float* __restrict__ W, const float* __restrict__ colLSE,
                       bhalf* __restrict__ eA, float* __restrict__ mA) {
  int i = blockIdx.x;
  int l = threadIdx.x;
  const float4* row = (const float4*)(W + (size_t)i * NN_);
  const float4* cls = (const float4*)colLSE;
  float4 v[4];
#pragma unroll
  for (int t = 0; t < 4; ++t) {
    float4 wv = row[t * 64 + l];
    float4 cv = cls[t * 64 + l];
    v[t].x = wv.x - cv.x; v[t].y = wv.y - cv.y;
    v[t].z = wv.z - cv.z; v[t].w = wv.w - cv.w;
  }
  float m = -1e30f;
#pragma unroll
  for (int t = 0; t < 4; ++t)
    m = fmaxf(m, fmaxf(fmaxf(v[t].x, v[t].y), fmaxf(v[t].z, v[t].w)));
#pragma unroll
  for (int off = 32; off; off >>= 1) m = fmaxf(m, __shfl_xor(m, off));
#pragma unroll
  for (int t = 0; t < 4; ++t) {
    bhalf4 o;
    o[0] = (bhalf)__expf(v[t].x - m);
    o[1] = (bhalf)__expf(v[t].y - m);
    o[2] = (bhalf)__expf(v[t].z - m);
    o[3] = (bhalf)__expf(v[t].w - m);
    *(bhalf4*)(eA + (size_t)i * NN_ + t * 256 + l * 4) = o;
  }
  if (l == 0) mA[i] = m;
}

// ---------------- K3: expB[b,k] = exp(la[b,k]-mB[b]), mB[b] ----------------
__global__ void k_expB(const float* __restrict__ LA,
                       bhalf* __restrict__ eB, float* __restrict__ mB) {
  int b = blockIdx.x;
  int l = threadIdx.x;
  const float4* row = (const float4*)(LA + (size_t)b * NN_);
  float4 v[4];
#pragma unroll
  for (int t = 0; t < 4; ++t) v[t] = row[t * 64 + l];
  float m = -1e30f;
#pragma unroll
  for (int t = 0; t < 4; ++t)
    m = fmaxf(m, fmaxf(fmaxf(v[t].x, v[t].y), fmaxf(v[t].z, v[t].w)));
#pragma unroll
  for (int off = 32; off; off >>= 1) m = fmaxf(m, __shfl_xor(m, off));
#pragma unroll
  for (int t = 0; t < 4; ++t) {
    bhalf4 o;
    o[0] = (bhalf)__expf(v[t].x - m);
    o[1] = (bhalf)__expf(v[t].y - m);
    o[2] = (bhalf)__expf(v[t].z - m);
    o[3] = (bhalf)__expf(v[t].w - m);
    *(bhalf4*)(eB + (size_t)b * NN_ + t * 256 + l * 4) = o;
  }
  if (l == 0) mB[b] = m;
}

// ---------------- GEMM: 256x256 tile, BK=64, 512 thr (8 waves 2Mx4N), 8-phase ----------------
// out[b,i] = log(sum_k eB[b,k]*eA[i,k]) + mB[b] + mA[i]
// LDS: 2 dbuf x (A 32KB + B 32KB) = 128KB. Half = 128 rows x 64k x 2B = 16KB.
// Stage schedule (phase (t,q)): q0: A-h0(t+1), q1: A-h1(t+1), q2: B-h0(t+2), q3: B-h1(t+2)
// vmcnt(4) once per K-tile at q3: guarantees all of K-tile t+1 landed, leaves B(t+2) in flight.
__global__ __launch_bounds__(512, 2) void k_gemm(const bhalf* __restrict__ A,  // eB [M][K]
                                                 const bhalf* __restrict__ Bt, // eA [N][K]
                                                 const float* __restrict__ mB,
                                                 const float* __restrict__ mA,
                                                 float* __restrict__ out) {
  __shared__ __align__(16) unsigned char lds[131072];

  const int nwg = gridDim.x;              // 256, %8==0
  const int wg  = blockIdx.x;
  const int swz = (wg & 7) * (nwg >> 3) + (wg >> 3);
  const int bm = swz >> 2;                // 0..63
  const int bn = swz & 3;                 // 0..3

  const int tid = threadIdx.x;
  const int l = tid & 63;
  const int w = tid >> 6;
  const int wr = w >> 2;                  // 0..1 (M)
  const int wc = w & 3;                   // 0..3 (N)

  // staging geometry: thread covers rows r8 and r8+64 of a 128-row half, chunk j=tid&7
  const int r8  = tid >> 3;               // 0..63
  const int kel = (((tid & 7) ^ (r8 & 7)) << 3);   // pre-swizzled source element offset
  const bhalf* A_blk = A  + (size_t)(bm * 256) * KK_;
  const bhalf* B_blk = Bt + (size_t)(bn * 256) * KK_;

  auto stA = [&](int t, int h) {
    unsigned char* dst = lds + (t & 1) * 65536 + h * 16384 + tid * 16;
    const bhalf* g = A_blk + (size_t)(h * 128 + r8) * KK_ + t * 64 + kel;
    gload_lds16(g, dst);
    gload_lds16(g + (size_t)64 * KK_, dst + 8192);
  };
  auto stB = [&](int t, int h) {
    unsigned char* dst = lds + (t & 1) * 65536 + 32768 + h * 16384 + tid * 16;
    const bhalf* g = B_blk + (size_t)(h * 128 + r8) * KK_ + t * 64 + kel;
    gload_lds16(g, dst);
    gload_lds16(g + (size_t)64 * KK_, dst + 8192);
  };

  const int kx  = 16 * (l >> 4);          // lane k-chunk byte
  const int x16 = (l & 7) << 4;           // read-side XOR (row&7)<<4, row%8 == l%8 always

  f32x4 zero = {0.f, 0.f, 0.f, 0.f};
  f32x4 acc[8][4];
#pragma unroll
  for (int m = 0; m < 8; ++m)
#pragma unroll
    for (int n = 0; n < 4; ++n) acc[m][n] = zero;

  // prologue: K-tile 0 (A+B) and B of K-tile 1. 12 loads; vmcnt(4) -> A0,B0 landed.
  stA(0, 0); stA(0, 1);
  stB(0, 0); stB(0, 1);
  stB(1, 0); stB(1, 1);
  asm volatile("s_waitcnt vmcnt(4)" ::: "memory");
  __builtin_amdgcn_s_barrier();

  const int NT = KK_ / 64;                // 16
  for (int t = 0; t < NT; ++t) {
    unsigned char* sAb = lds + (t & 1) * 65536;
    unsigned char* sBb = sAb + 32768;
    bhalf8 bq[4][2];
#pragma unroll
    for (int q = 0; q < 4; ++q) {
      bhalf8 af[2][2];
#pragma unroll
      for (int m = 0; m < 2; ++m) {
        const int row = wr * 128 + q * 32 + m * 16 + (l & 15);
#pragma unroll
        for (int kk = 0; kk < 2; ++kk)
          af[m][kk] = *(const bhalf8*)(sAb + row * 128 + ((kk * 64 + kx) ^ x16));
      }
      if (q == 0) {
#pragma unroll
        for (int n = 0; n < 4; ++n) {
          const int row = wc * 64 + n * 16 + (l & 15);
#pragma unroll
          for (int kk = 0; kk < 2; ++kk)
            bq[n][kk] = *(const bhalf8*)(sBb + row * 128 + ((kk * 64 + kx) ^ x16));
        }
      }
      // staging (clamped at tail: re-writes identical data into dead/identical slots)
      if (q == 0)      stA(t + 1 < NT ? t + 1 : NT - 1, 0);
      else if (q == 1) stA(t + 1 < NT ? t + 1 : NT - 1, 1);
      else if (q == 2) stB(t + 2 < NT ? t + 2 : NT - 1, 0);
      else             stB(t + 2 < NT ? t + 2 : NT - 1, 1);

      if (q == 3) asm volatile("s_waitcnt vmcnt(4)" ::: "memory");
      __builtin_amdgcn_s_barrier();
      asm volatile("s_waitcnt lgkmcnt(0)" ::: "memory");
      __builtin_amdgcn_sched_barrier(0);
      __builtin_amdgcn_s_setprio(1);
#pragma unroll
      for (int m = 0; m < 2; ++m)
#pragma unroll
        for (int n = 0; n < 4; ++n)
#pragma unroll
          for (int kk = 0; kk < 2; ++kk)
            acc[2 * q + m][n] =
                __builtin_amdgcn_mfma_f32_16x16x32_bf16(af[m][kk], bq[n][kk], acc[2 * q + m][n], 0, 0, 0);
      __builtin_amdgcn_s_setprio(0);
      __builtin_amdgcn_s_barrier();
    }
  }

  // epilogue: D row = 4*(l>>4)+r (+16 per m-frag), col = l&15 (+16 per n-frag)
  const int c0 = bn * 256 + wc * 64 + (l & 15);
  const int r0 = bm * 256 + wr * 128 + (l >> 4) * 4;
  float mav[4];
#pragma unroll
  for (int nf = 0; nf < 4; ++nf) mav[nf] = mA[c0 + nf * 16];
#pragma unroll
  for (int mf = 0; mf < 8; ++mf) {
#pragma unroll
    for (int r = 0; r < 4; ++r) {
      const int row = r0 + mf * 16 + r;
      const float mb = mB[row];
      float* o = out + (size_t)row * NN_ + c0;
#pragma unroll
      for (int nf = 0; nf < 4; ++nf)
        o[nf * 16] = __logf(acc[mf][nf][r]) + mb + mav[nf];
    }
  }
}

extern "C" void kernel_launch(void* const* d_in, const int* in_sizes, int n_in,
                              void* d_out, int out_size, void* d_ws, size_t ws_size,
                              hipStream_t stream) {
  const float* log_alpha = (const float*)d_in[0];  // [16384,1024] f32
  const float* W         = (const float*)d_in[1];  // [1024,1024] f32
  float* out = (float*)d_out;                      // [16384,1024] f32

  uintptr_t ws = (uintptr_t)d_ws;
  bhalf* eB     = (bhalf*)(ws);                    // 33,554,432 B
  bhalf* eA     = (bhalf*)(ws + 33554432);         //  2,097,152 B
  float* mB     = (float*)(ws + 35651584);         //     65,536 B
  float* mA     = (float*)(ws + 35717120);         //      4,096 B
  float* colLSE = (float*)(ws + 35721216);         //      4,096 B
  float* pM     = (float*)(ws + 35725312);         //    131,072 B
  float* pS     = (float*)(ws + 35856384);         //    131,072 B

  k_colpart<<<dim3(4, 32), 256, 0, stream>>>(W, pM, pS);
  k_colfin<<<4, 256, 0, stream>>>(pM, pS, colLSE);
  k_expA<<<NN_, 64, 0, stream>>>(W, colLSE, eA, mA);
  k_expB<<<MB_, 64, 0, stream>>>(log_alpha, eB, mB);
  k_gemm<<<(MB_ / 256) * (NN_ / 256), 512, 0, stream>>>(eB, eA, mB, mA, out);
}